// Round 1
// baseline (229.248 us; speedup 1.0000x reference)
//
#include <hip/hip_runtime.h>
#include <hip/hip_bf16.h>

// Problem constants (fixed-shape problem)
#define NNODES 20000
#define KNB    32
#define DEMB   128
#define HIDN   100
#define OUTU   20
#define HHEADS 5
#define OUTW   228   // H*OUT + D = 100 + 128

typedef __attribute__((ext_vector_type(4))) float f32x4;
typedef __attribute__((ext_vector_type(8))) short bf16x8;

__device__ __forceinline__ unsigned short f2bf(float f) {
    union { float f; unsigned u; } v; v.f = f;
    unsigned r = (v.u + 0x7fffu + ((v.u >> 16) & 1u)) >> 16;
    return (unsigned short)r;
}

// ---------------- prep: W1t (112x256 bf16, rows j>=100 zero) and W2t (32x128 bf16) ----------------
__global__ void sa_prep(const float* __restrict__ W1, const float* __restrict__ W2,
                        unsigned short* __restrict__ W1t, unsigned short* __restrict__ W2t) {
    int idx = blockIdx.x * 256 + threadIdx.x;
    if (idx < 112 * 256) {
        int j = idx >> 8, d = idx & 255;            // W1t[j][d] = W1[d][j], d in [0,256): neigh+node halves
        float v = (j < HIDN) ? W1[d * HIDN + j] : 0.f;
        W1t[idx] = f2bf(v);
    } else {
        int i2 = idx - 112 * 256;
        if (i2 < 32 * 128) {
            int o = i2 >> 7, jj = i2 & 127;         // W2t[o][j] = W2[j][o], zero-padded
            float v = (o < OUTU && jj < HIDN) ? W2[jj * OUTU + o] : 0.f;
            W2t[i2] = f2bf(v);
        }
    }
}

// ---------------- main: one wave (64 threads) per node ----------------
__global__ __launch_bounds__(64)
void sa_main(const float* __restrict__ emb,
             const int* __restrict__ node_idx,
             const int* __restrict__ neigh_idx,
             const float* __restrict__ b1,
             const float* __restrict__ b2,
             const float* __restrict__ Wa,
             const float* __restrict__ ba,
             const unsigned short* __restrict__ W1t,
             const unsigned short* __restrict__ W2t,
             float* __restrict__ out) {
    __shared__ unsigned short xn_s[32 * 136];   // neighbor embeddings bf16, padded stride 136
    __shared__ unsigned short xnode_s[136];     // node embedding bf16
    __shared__ unsigned short hid_s[32 * 136];  // hidden (relu) bf16, cols >=100 zero
    __shared__ float tT_s[20 * 36];             // t transposed: [o][m], padded stride 36
    __shared__ float pf_s[160];                 // p flat (row-major [k][h] flatten), 32*5

    const int lane = threadIdx.x;
    const int n = blockIdx.x;
    const int l15 = lane & 15, h4 = lane >> 4;

    // ---- stage neighbor rows (f32 -> bf16) ----
    {
        int m = lane >> 1, half = lane & 1;
        const float* rowp = emb + (size_t)neigh_idx[n * KNB + m] * DEMB + half * 64;
#pragma unroll
        for (int w = 0; w < 16; ++w) {
            float4 f = ((const float4*)rowp)[w];
            ushort4 u = make_ushort4(f2bf(f.x), f2bf(f.y), f2bf(f.z), f2bf(f.w));
            *(ushort4*)&xn_s[m * 136 + half * 64 + w * 4] = u;
        }
    }
    // ---- stage node row + write node part of output ----
    {
        int nid = node_idx[n];
        if (lane < 32) {
            float4 f = ((const float4*)(emb + (size_t)nid * DEMB))[lane];
            ushort4 u = make_ushort4(f2bf(f.x), f2bf(f.y), f2bf(f.z), f2bf(f.w));
            *(ushort4*)&xnode_s[lane * 4] = u;
            ((float4*)(out + (size_t)n * OUTW + HHEADS * OUTU))[lane] = f;
        }
    }
    // ---- zero hid tail cols [112,128) (cols [100,112) become zero via zero W1t rows + zero bias) ----
    {
        int r = lane >> 1, c = 112 + (lane & 1) * 8;
        ushort4 z = make_ushort4(0, 0, 0, 0);
        *(ushort4*)&hid_s[r * 136 + c] = z;
        *(ushort4*)&hid_s[r * 136 + c + 4] = z;
    }
    __syncthreads();

    // ---- GEMM1: D1[j][m] = sum_d W1t[j][d] * xext[m][d], j-tiles=7, m-tiles=2, K=256 (8 steps) ----
    f32x4 acc1[7][2] = {};
    {
        const unsigned short* w1p = W1t + (size_t)l15 * 256 + h4 * 8;
#pragma unroll
        for (int ks = 0; ks < 8; ++ks) {
            bf16x8 bfr0, bfr1;
            if (ks < 4) {
                bfr0 = *(const bf16x8*)&xn_s[l15 * 136 + ks * 32 + h4 * 8];
                bfr1 = *(const bf16x8*)&xn_s[(16 + l15) * 136 + ks * 32 + h4 * 8];
            } else {
                bf16x8 bn = *(const bf16x8*)&xnode_s[(ks - 4) * 32 + h4 * 8];
                bfr0 = bn; bfr1 = bn;
            }
#pragma unroll
            for (int jt = 0; jt < 7; ++jt) {
                bf16x8 afr = *(const bf16x8*)(w1p + jt * 16 * 256 + ks * 32);
                acc1[jt][0] = __builtin_amdgcn_mfma_f32_16x16x32_bf16(afr, bfr0, acc1[jt][0], 0, 0, 0);
                acc1[jt][1] = __builtin_amdgcn_mfma_f32_16x16x32_bf16(afr, bfr1, acc1[jt][1], 0, 0, 0);
            }
        }
    }
    // ---- hid = relu(D1 + b1), write bf16 transposed back to [m][j] ----
#pragma unroll
    for (int jt = 0; jt < 7; ++jt) {
        int j0 = jt * 16 + h4 * 4;
        float4 bv;
        if (j0 + 3 < HIDN) bv = *(const float4*)(b1 + j0);
        else bv = make_float4(0.f, 0.f, 0.f, 0.f);   // j0 in {100,104,108}: acc is 0 there too
#pragma unroll
        for (int mt = 0; mt < 2; ++mt) {
            int mm = mt * 16 + l15;
            f32x4 a = acc1[jt][mt];
            ushort4 hv = make_ushort4(f2bf(fmaxf(a[0] + bv.x, 0.f)),
                                      f2bf(fmaxf(a[1] + bv.y, 0.f)),
                                      f2bf(fmaxf(a[2] + bv.z, 0.f)),
                                      f2bf(fmaxf(a[3] + bv.w, 0.f)));
            *(ushort4*)&hid_s[mm * 136 + j0] = hv;
        }
    }
    __syncthreads();

    // ---- GEMM2: D2[m][o] = sum_j hid[m][j] * W2[j][o], K=128 (4 steps) ----
    f32x4 acc2[2][2] = {};
    {
#pragma unroll
        for (int ks = 0; ks < 4; ++ks) {
            bf16x8 afr0 = *(const bf16x8*)&hid_s[l15 * 136 + ks * 32 + h4 * 8];
            bf16x8 afr1 = *(const bf16x8*)&hid_s[(16 + l15) * 136 + ks * 32 + h4 * 8];
            bf16x8 bfr0 = *(const bf16x8*)(W2t + l15 * 128 + ks * 32 + h4 * 8);
            bf16x8 bfr1 = *(const bf16x8*)(W2t + (16 + l15) * 128 + ks * 32 + h4 * 8);
            acc2[0][0] = __builtin_amdgcn_mfma_f32_16x16x32_bf16(afr0, bfr0, acc2[0][0], 0, 0, 0);
            acc2[0][1] = __builtin_amdgcn_mfma_f32_16x16x32_bf16(afr0, bfr1, acc2[0][1], 0, 0, 0);
            acc2[1][0] = __builtin_amdgcn_mfma_f32_16x16x32_bf16(afr1, bfr0, acc2[1][0], 0, 0, 0);
            acc2[1][1] = __builtin_amdgcn_mfma_f32_16x16x32_bf16(afr1, bfr1, acc2[1][1], 0, 0, 0);
        }
    }
    // ---- t = relu(D2 + b2), store transposed tT[o][m] as f32 ----
#pragma unroll
    for (int ot = 0; ot < 2; ++ot) {
        int o = ot * 16 + l15;
        if (o < OUTU) {
            float b2v = b2[o];
#pragma unroll
            for (int mt = 0; mt < 2; ++mt) {
                int m0 = mt * 16 + h4 * 4;
                f32x4 a = acc2[mt][ot];
                float4 tv = make_float4(fmaxf(a[0] + b2v, 0.f), fmaxf(a[1] + b2v, 0.f),
                                        fmaxf(a[2] + b2v, 0.f), fmaxf(a[3] + b2v, 0.f));
                *(float4*)&tT_s[o * 36 + m0] = tv;
            }
        }
    }
    __syncthreads();

    // ---- attention: att[m][h] = relu(t[m] . Wa[:,h] + ba[h]); softmax over h; store p flat [m*5+h] ----
    {
        int mm = lane & 31;
        float tv[20];
#pragma unroll
        for (int o = 0; o < OUTU; ++o) tv[o] = tT_s[o * 36 + mm];
        float att[5];
#pragma unroll
        for (int h = 0; h < HHEADS; ++h) {
            float s = ba[h];                       // uniform -> scalar loads
#pragma unroll
            for (int o = 0; o < OUTU; ++o) s += tv[o] * Wa[o * HHEADS + h];
            att[h] = fmaxf(s, 0.f);
        }
        float mx = att[0];
#pragma unroll
        for (int h = 1; h < HHEADS; ++h) mx = fmaxf(mx, att[h]);
        float e[5], sum = 0.f;
#pragma unroll
        for (int h = 0; h < HHEADS; ++h) { e[h] = __expf(att[h] - mx); sum += e[h]; }
        float inv = 1.f / sum;
        if (lane < 32) {
#pragma unroll
            for (int h = 0; h < HHEADS; ++h) pf_s[mm * HHEADS + h] = e[h] * inv;
        }
    }
    __syncthreads();

    // ---- aggregate: out[n, h*20+o] = sum_k pf[h*32+k] * t[k][o]  (reshape-faithful) ----
#pragma unroll
    for (int pass = 0; pass < 2; ++pass) {
        int idx = pass * 64 + lane;
        if (idx < HHEADS * OUTU) {
            int h = idx / OUTU, o = idx % OUTU;
            float s = 0.f;
#pragma unroll
            for (int kk = 0; kk < 8; ++kk) {
                float4 p4 = *(const float4*)&pf_s[h * 32 + kk * 4];
                float4 t4 = *(const float4*)&tT_s[o * 36 + kk * 4];
                s += p4.x * t4.x + p4.y * t4.y + p4.z * t4.z + p4.w * t4.w;
            }
            out[(size_t)n * OUTW + idx] = s;
        }
    }
}

extern "C" void kernel_launch(void* const* d_in, const int* in_sizes, int n_in,
                              void* d_out, int out_size, void* d_ws, size_t ws_size,
                              hipStream_t stream) {
    const float* emb      = (const float*)d_in[0];
    const int*   node_idx = (const int*)d_in[1];
    const int*   neigh_idx= (const int*)d_in[2];
    const float* W1       = (const float*)d_in[3];
    const float* b1       = (const float*)d_in[4];
    const float* W2       = (const float*)d_in[5];
    const float* b2       = (const float*)d_in[6];
    const float* Wa       = (const float*)d_in[7];
    const float* ba       = (const float*)d_in[8];
    float* out = (float*)d_out;

    unsigned short* W1t = (unsigned short*)d_ws;            // 112*256 bf16 = 57344 B
    unsigned short* W2t = W1t + 112 * 256;                  // 32*128 bf16  =  8192 B

    int n = in_sizes[1];                                    // 20000 nodes

    sa_prep<<<(112 * 256 + 32 * 128 + 255) / 256, 256, 0, stream>>>(W1, W2, W1t, W2t);
    sa_main<<<n, 64, 0, stream>>>(emb, node_idx, neigh_idx, b1, b2, Wa, ba, W1t, W2t, out);
}

// Round 2
// 212.231 us; speedup vs baseline: 1.0802x; 1.0802x over previous
//
#include <hip/hip_runtime.h>
#include <hip/hip_bf16.h>

// Problem constants (fixed-shape problem)
#define NNODES 20000
#define KNB    32
#define DEMB   128
#define HIDN   100
#define OUTU   20
#define HHEADS 5
#define OUTW   228   // H*OUT + D = 100 + 128

typedef __attribute__((ext_vector_type(4))) float f32x4;
typedef __attribute__((ext_vector_type(8))) short bf16x8;

__device__ __forceinline__ unsigned short f2bf(float f) {
    union { float f; unsigned u; } v; v.f = f;
    unsigned r = (v.u + 0x7fffu + ((v.u >> 16) & 1u)) >> 16;
    return (unsigned short)r;
}

// pack 2 f32 -> 2 bf16 in one VALU op (RNE)
__device__ __forceinline__ unsigned pkbf(float lo, float hi) {
    unsigned r;
    asm("v_cvt_pk_bf16_f32 %0, %1, %2" : "=v"(r) : "v"(lo), "v"(hi));
    return r;
}
__device__ __forceinline__ bf16x8 cvt8(float4 a, float4 b) {
    union { unsigned u[4]; bf16x8 v; } t;
    t.u[0] = pkbf(a.x, a.y); t.u[1] = pkbf(a.z, a.w);
    t.u[2] = pkbf(b.x, b.y); t.u[3] = pkbf(b.z, b.w);
    return t.v;
}

// ---------------- prep: W1t (112x256 bf16, rows j>=100 zero) and W2t (32x128 bf16) ----------------
__global__ void sa_prep(const float* __restrict__ W1, const float* __restrict__ W2,
                        unsigned short* __restrict__ W1t, unsigned short* __restrict__ W2t) {
    int idx = blockIdx.x * 256 + threadIdx.x;
    if (idx < 112 * 256) {
        int j = idx >> 8, d = idx & 255;            // W1t[j][d] = W1[d][j]
        float v = (j < HIDN) ? W1[d * HIDN + j] : 0.f;
        W1t[idx] = f2bf(v);
    } else {
        int i2 = idx - 112 * 256;
        if (i2 < 32 * 128) {
            int o = i2 >> 7, jj = i2 & 127;         // W2t[o][j] = W2[j][o], zero-padded
            float v = (o < OUTU && jj < HIDN) ? W2[jj * OUTU + o] : 0.f;
            W2t[i2] = f2bf(v);
        }
    }
}

// ---------------- main: one wave (64 threads) per node ----------------
// LDS ~12.2 KB/block -> ~13 blocks/CU; launch_bounds(64,3) caps VGPR at 168 (3 waves/SIMD).
__global__ __launch_bounds__(64, 3)
void sa_main(const float* __restrict__ emb,
             const int* __restrict__ node_idx,
             const int* __restrict__ neigh_idx,
             const float* __restrict__ b1,
             const float* __restrict__ b2,
             const float* __restrict__ Wa,
             const float* __restrict__ ba,
             const unsigned short* __restrict__ W1t,
             const unsigned short* __restrict__ W2t,
             float* __restrict__ out) {
    __shared__ unsigned short hid_s[32 * 136];  // hidden (relu) bf16, cols >=100 zero; stride 136 -> 2-way max (free)
    __shared__ float tT_s[20 * 36];             // t transposed: [o][m], padded stride 36
    __shared__ float pf_s[160];                 // p flat (row-major [k][h] flatten), 32*5

    const int lane = threadIdx.x;
    const int n = blockIdx.x;
    const int l15 = lane & 15, h4 = lane >> 4;

    // ---- gather pointers: B-fragment layout is "lane l15 = row, 8 contiguous d at h4*8" ----
    const int* nip = neigh_idx + (size_t)n * KNB;
    const int r0 = nip[l15];           // m-tile 0 columns
    const int r1 = nip[16 + l15];      // m-tile 1 columns
    const int nid = node_idx[n];
    const float* p0 = emb + (size_t)r0 * DEMB + h4 * 8;
    const float* p1 = emb + (size_t)r1 * DEMB + h4 * 8;
    const float* pn = emb + (size_t)nid * DEMB + h4 * 8;

    // ---- node part of output (direct copy, coalesced) ----
    if (lane < 32) {
        float4 f = ((const float4*)(emb + (size_t)nid * DEMB))[lane];
        ((float4*)(out + (size_t)n * OUTW + HHEADS * OUTU))[lane] = f;
    }

    // ---- zero hid tail cols [112,128) (cols [100,112) are zero via zero W1t rows + zero bias) ----
    {
        int r = lane >> 1, c = 112 + (lane & 1) * 8;
        ushort4 z = make_ushort4(0, 0, 0, 0);
        *(ushort4*)&hid_s[r * 136 + c] = z;
        *(ushort4*)&hid_s[r * 136 + c + 4] = z;
    }

    // ---- GEMM1: D1[j][m] = sum_d W1t[j][d] * xext[m][d]; B-frags straight from global ----
    f32x4 acc1[7][2] = {};
    {
        const unsigned short* w1p = W1t + (size_t)l15 * 256 + h4 * 8;
#pragma unroll
        for (int ks = 0; ks < 8; ++ks) {
            bf16x8 bfr0, bfr1;
            if (ks < 4) {
                float4 a0 = *(const float4*)(p0 + ks * 32);
                float4 c0 = *(const float4*)(p0 + ks * 32 + 4);
                float4 a1 = *(const float4*)(p1 + ks * 32);
                float4 c1 = *(const float4*)(p1 + ks * 32 + 4);
                bfr0 = cvt8(a0, c0);
                bfr1 = cvt8(a1, c1);
            } else {
                float4 a = *(const float4*)(pn + (ks - 4) * 32);
                float4 c = *(const float4*)(pn + (ks - 4) * 32 + 4);
                bfr0 = cvt8(a, c);
                bfr1 = bfr0;
            }
#pragma unroll
            for (int jt = 0; jt < 7; ++jt) {
                bf16x8 afr = *(const bf16x8*)(w1p + jt * 16 * 256 + ks * 32);
                acc1[jt][0] = __builtin_amdgcn_mfma_f32_16x16x32_bf16(afr, bfr0, acc1[jt][0], 0, 0, 0);
                acc1[jt][1] = __builtin_amdgcn_mfma_f32_16x16x32_bf16(afr, bfr1, acc1[jt][1], 0, 0, 0);
            }
        }
    }
    // ---- hid = relu(D1 + b1), write bf16 transposed back to [m][j] ----
#pragma unroll
    for (int jt = 0; jt < 7; ++jt) {
        int j0 = jt * 16 + h4 * 4;
        float4 bv;
        if (j0 + 3 < HIDN) bv = *(const float4*)(b1 + j0);
        else bv = make_float4(0.f, 0.f, 0.f, 0.f);   // j0 in {100,104,108}: acc is 0 there too
#pragma unroll
        for (int mt = 0; mt < 2; ++mt) {
            int mm = mt * 16 + l15;
            f32x4 a = acc1[jt][mt];
            ushort4 hv = make_ushort4(f2bf(fmaxf(a[0] + bv.x, 0.f)),
                                      f2bf(fmaxf(a[1] + bv.y, 0.f)),
                                      f2bf(fmaxf(a[2] + bv.z, 0.f)),
                                      f2bf(fmaxf(a[3] + bv.w, 0.f)));
            *(ushort4*)&hid_s[mm * 136 + j0] = hv;
        }
    }
    __syncthreads();

    // ---- GEMM2: D2[m][o] = sum_j hid[m][j] * W2[j][o], K=128 (4 steps) ----
    f32x4 acc2[2][2] = {};
    {
#pragma unroll
        for (int ks = 0; ks < 4; ++ks) {
            bf16x8 afr0 = *(const bf16x8*)&hid_s[l15 * 136 + ks * 32 + h4 * 8];
            bf16x8 afr1 = *(const bf16x8*)&hid_s[(16 + l15) * 136 + ks * 32 + h4 * 8];
            bf16x8 bfr0 = *(const bf16x8*)(W2t + l15 * 128 + ks * 32 + h4 * 8);
            bf16x8 bfr1 = *(const bf16x8*)(W2t + (16 + l15) * 128 + ks * 32 + h4 * 8);
            acc2[0][0] = __builtin_amdgcn_mfma_f32_16x16x32_bf16(afr0, bfr0, acc2[0][0], 0, 0, 0);
            acc2[0][1] = __builtin_amdgcn_mfma_f32_16x16x32_bf16(afr0, bfr1, acc2[0][1], 0, 0, 0);
            acc2[1][0] = __builtin_amdgcn_mfma_f32_16x16x32_bf16(afr1, bfr0, acc2[1][0], 0, 0, 0);
            acc2[1][1] = __builtin_amdgcn_mfma_f32_16x16x32_bf16(afr1, bfr1, acc2[1][1], 0, 0, 0);
        }
    }
    // ---- t = relu(D2 + b2), store transposed tT[o][m] as f32 ----
#pragma unroll
    for (int ot = 0; ot < 2; ++ot) {
        int o = ot * 16 + l15;
        if (o < OUTU) {
            float b2v = b2[o];
#pragma unroll
            for (int mt = 0; mt < 2; ++mt) {
                int m0 = mt * 16 + h4 * 4;
                f32x4 a = acc2[mt][ot];
                float4 tv = make_float4(fmaxf(a[0] + b2v, 0.f), fmaxf(a[1] + b2v, 0.f),
                                        fmaxf(a[2] + b2v, 0.f), fmaxf(a[3] + b2v, 0.f));
                *(float4*)&tT_s[o * 36 + m0] = tv;
            }
        }
    }
    __syncthreads();

    // ---- attention: att[m][h] = relu(t[m] . Wa[:,h] + ba[h]); softmax over h; store p flat [m*5+h] ----
    {
        int mm = lane & 31;
        float tv[20];
#pragma unroll
        for (int o = 0; o < OUTU; ++o) tv[o] = tT_s[o * 36 + mm];
        float att[5];
#pragma unroll
        for (int h = 0; h < HHEADS; ++h) {
            float s = ba[h];                       // uniform -> scalar loads
#pragma unroll
            for (int o = 0; o < OUTU; ++o) s += tv[o] * Wa[o * HHEADS + h];
            att[h] = fmaxf(s, 0.f);
        }
        float mx = att[0];
#pragma unroll
        for (int h = 1; h < HHEADS; ++h) mx = fmaxf(mx, att[h]);
        float e[5], sum = 0.f;
#pragma unroll
        for (int h = 0; h < HHEADS; ++h) { e[h] = __expf(att[h] - mx); sum += e[h]; }
        float inv = 1.f / sum;
        if (lane < 32) {
#pragma unroll
            for (int h = 0; h < HHEADS; ++h) pf_s[mm * HHEADS + h] = e[h] * inv;
        }
    }
    __syncthreads();

    // ---- aggregate: out[n, h*20+o] = sum_k pf[h*32+k] * t[k][o]  (reshape-faithful) ----
#pragma unroll
    for (int pass = 0; pass < 2; ++pass) {
        int idx = pass * 64 + lane;
        if (idx < HHEADS * OUTU) {
            int h = idx / OUTU, o = idx % OUTU;
            float s = 0.f;
#pragma unroll
            for (int kk = 0; kk < 8; ++kk) {
                float4 p4 = *(const float4*)&pf_s[h * 32 + kk * 4];
                float4 t4 = *(const float4*)&tT_s[o * 36 + kk * 4];
                s += p4.x * t4.x + p4.y * t4.y + p4.z * t4.z + p4.w * t4.w;
            }
            out[(size_t)n * OUTW + idx] = s;
        }
    }
}

extern "C" void kernel_launch(void* const* d_in, const int* in_sizes, int n_in,
                              void* d_out, int out_size, void* d_ws, size_t ws_size,
                              hipStream_t stream) {
    const float* emb      = (const float*)d_in[0];
    const int*   node_idx = (const int*)d_in[1];
    const int*   neigh_idx= (const int*)d_in[2];
    const float* W1       = (const float*)d_in[3];
    const float* b1       = (const float*)d_in[4];
    const float* W2       = (const float*)d_in[5];
    const float* b2       = (const float*)d_in[6];
    const float* Wa       = (const float*)d_in[7];
    const float* ba       = (const float*)d_in[8];
    float* out = (float*)d_out;

    unsigned short* W1t = (unsigned short*)d_ws;            // 112*256 bf16 = 57344 B
    unsigned short* W2t = W1t + 112 * 256;                  // 32*128 bf16  =  8192 B

    int n = in_sizes[1];                                    // 20000 nodes

    sa_prep<<<(112 * 256 + 32 * 128 + 255) / 256, 256, 0, stream>>>(W1, W2, W1t, W2t);
    sa_main<<<n, 64, 0, stream>>>(emb, node_idx, neigh_idx, b1, b2, Wa, ba, W1t, W2t, out);
}

// Round 3
// 139.696 us; speedup vs baseline: 1.6410x; 1.5192x over previous
//
#include <hip/hip_runtime.h>
#include <hip/hip_bf16.h>

// Problem constants (fixed-shape problem)
#define NNODES 20000
#define KNB    32
#define DEMB   128
#define HIDN   100
#define OUTU   20
#define HHEADS 5
#define OUTW   228   // H*OUT + D = 100 + 128

#define NWAVES 8     // waves per block, 1 node per wave

typedef __attribute__((ext_vector_type(4))) float f32x4;
typedef __attribute__((ext_vector_type(8))) short bf16x8;

__device__ __forceinline__ unsigned short f2bf(float f) {
    union { float f; unsigned u; } v; v.f = f;
    unsigned r = (v.u + 0x7fffu + ((v.u >> 16) & 1u)) >> 16;
    return (unsigned short)r;
}

// pack 2 f32 -> 2 bf16 in one VALU op (RNE)
__device__ __forceinline__ unsigned pkbf(float lo, float hi) {
    unsigned r;
    asm("v_cvt_pk_bf16_f32 %0, %1, %2" : "=v"(r) : "v"(lo), "v"(hi));
    return r;
}
__device__ __forceinline__ bf16x8 cvt8(float4 a, float4 b) {
    union { unsigned u[4]; bf16x8 v; } t;
    t.u[0] = pkbf(a.x, a.y); t.u[1] = pkbf(a.z, a.w);
    t.u[2] = pkbf(b.x, b.y); t.u[3] = pkbf(b.z, b.w);
    return t.v;
}

// ---------------- prep: swizzled W1t (112x256 bf16) and W2t (32x128 bf16) ----------------
// T2-style XOR swizzle baked into the GLOBAL layout; main kernel stages LDS linearly and
// reads with the same XOR -> conflict-free ds_read_b128 at 512B/256B row strides.
__global__ void sa_prep(const float* __restrict__ W1, const float* __restrict__ W2,
                        unsigned short* __restrict__ W1t, unsigned short* __restrict__ W2t) {
    int idx = blockIdx.x * 256 + threadIdx.x;
    if (idx < 112 * 256) {
        int j = idx >> 8, d = idx & 255;            // logical W1t[j][d] = W1[d][j]
        float v = (j < HIDN) ? W1[d * HIDN + j] : 0.f;
        W1t[(j << 8) | (d ^ ((j & 7) << 3))] = f2bf(v);   // xor elem bits 3..5 by row
    } else {
        int i2 = idx - 112 * 256;
        if (i2 < 32 * 128) {
            int o = i2 >> 7, jj = i2 & 127;         // logical W2t[o][j] = W2[j][o]
            float v = (o < OUTU && jj < HIDN) ? W2[jj * OUTU + o] : 0.f;
            W2t[(o << 7) | (jj ^ ((o & 7) << 3))] = f2bf(v);
        }
    }
}

// swizzled LDS readers (byte-offset XOR matches prep's element XOR)
__device__ __forceinline__ bf16x8 ld_w1(const unsigned short* w1_lds, int j, int d0) {
    int off = j * 512 + ((d0 * 2) ^ ((j & 7) << 4));
    return *(const bf16x8*)((const char*)w1_lds + off);
}
__device__ __forceinline__ bf16x8 ld_w2(const unsigned short* w2_lds, int o, int j0) {
    int off = o * 256 + ((j0 * 2) ^ ((o & 7) << 4));
    return *(const bf16x8*)((const char*)w2_lds + off);
}

// ---------------- main: 8 waves/block, 1 node/wave; W1t/W2t staged in LDS once ----------------
// LDS: 57344 (W1) + 8192 (W2) + 8*12224 (per-wave hid/tT/pf) = 163328 B -> 1 block/CU.
__global__ __launch_bounds__(NWAVES * 64, 2)
void sa_main(const float* __restrict__ emb,
             const int* __restrict__ node_idx,
             const int* __restrict__ neigh_idx,
             const float* __restrict__ b1,
             const float* __restrict__ b2,
             const float* __restrict__ Wa,
             const float* __restrict__ ba,
             const unsigned short* __restrict__ W1t,
             const unsigned short* __restrict__ W2t,
             float* __restrict__ out, int nnodes) {
    extern __shared__ char smem[];
    unsigned short* w1_lds = (unsigned short*)smem;                  // 57344 B
    unsigned short* w2_lds = (unsigned short*)(smem + 57344);        // 8192 B

    const int tid  = threadIdx.x;
    const int lane = tid & 63;
    const int wid  = tid >> 6;
    const int l15 = lane & 15, h4 = lane >> 4;

    char* wbase = smem + 65536 + wid * 12224;
    unsigned short* hid_s = (unsigned short*)wbase;                  // 32*136*2 = 8704 B
    float* tT_s = (float*)(wbase + 8704);                            // 20*36*4  = 2880 B
    float* pf_s = (float*)(wbase + 8704 + 2880);                     // 160*4    = 640 B

    int node = blockIdx.x * NWAVES + wid;
    const int active = (node < nnodes);
    if (node >= nnodes) node = nnodes - 1;   // clamp; all waves must reach the barrier

    // ---- issue gathers early (f32), overlap with LDS staging ----
    const int* nip = neigh_idx + (size_t)node * KNB;
    const int r0 = nip[l15];
    const int r1 = nip[16 + l15];
    const int nid = node_idx[node];
    const float* p0 = emb + (size_t)r0 * DEMB + h4 * 8;
    const float* p1 = emb + (size_t)r1 * DEMB + h4 * 8;
    const float* pn = emb + (size_t)nid * DEMB + h4 * 8;

    float4 ga0[4], gc0[4], ga1[4], gc1[4], na0[4], nc0[4];
#pragma unroll
    for (int ks = 0; ks < 4; ++ks) {
        ga0[ks] = *(const float4*)(p0 + ks * 32);
        gc0[ks] = *(const float4*)(p0 + ks * 32 + 4);
        ga1[ks] = *(const float4*)(p1 + ks * 32);
        gc1[ks] = *(const float4*)(p1 + ks * 32 + 4);
        na0[ks] = *(const float4*)(pn + ks * 32);
        nc0[ks] = *(const float4*)(pn + ks * 32 + 4);
    }
    // node part of output (full f32, coalesced)
    float4 nodecp;
    if (lane < 32) nodecp = ((const float4*)(emb + (size_t)nid * DEMB))[lane];

    // ---- cooperative staging of W1t/W2t into LDS (linear copy of pre-swizzled globals) ----
#pragma unroll
    for (int i = 0; i < 7; ++i)
        ((float4*)w1_lds)[tid + i * (NWAVES * 64)] = ((const float4*)W1t)[tid + i * (NWAVES * 64)];
    ((float4*)w2_lds)[tid] = ((const float4*)W2t)[tid];

    // convert gathers to bf16 fragments while staging drains
    bf16x8 bf0[4], bf1[4], bnn[4];
#pragma unroll
    for (int ks = 0; ks < 4; ++ks) {
        bf0[ks] = cvt8(ga0[ks], gc0[ks]);
        bf1[ks] = cvt8(ga1[ks], gc1[ks]);
        bnn[ks] = cvt8(na0[ks], nc0[ks]);
    }

    // zero hid tail cols [112,128)
    {
        int r = lane >> 1, c = 112 + (lane & 1) * 8;
        ushort4 z = make_ushort4(0, 0, 0, 0);
        *(ushort4*)&hid_s[r * 136 + c] = z;
        *(ushort4*)&hid_s[r * 136 + c + 4] = z;
    }

    __syncthreads();   // the only cross-wave barrier

    if (active && lane < 32)
        ((float4*)(out + (size_t)node * OUTW + HHEADS * OUTU))[lane] = nodecp;

    // ---- GEMM1: D1[j][m] = sum_d W1t[j][d] * xext[m][d]; A from LDS, B in regs ----
    f32x4 acc1[7][2] = {};
#pragma unroll
    for (int ks = 0; ks < 8; ++ks) {
        bf16x8 bfr0 = (ks < 4) ? bf0[ks & 3] : bnn[ks & 3];
        bf16x8 bfr1 = (ks < 4) ? bf1[ks & 3] : bnn[ks & 3];
#pragma unroll
        for (int jt = 0; jt < 7; ++jt) {
            bf16x8 afr = ld_w1(w1_lds, jt * 16 + l15, ks * 32 + h4 * 8);
            acc1[jt][0] = __builtin_amdgcn_mfma_f32_16x16x32_bf16(afr, bfr0, acc1[jt][0], 0, 0, 0);
            acc1[jt][1] = __builtin_amdgcn_mfma_f32_16x16x32_bf16(afr, bfr1, acc1[jt][1], 0, 0, 0);
        }
    }

    // ---- hid = relu(D1 + b1), write bf16 transposed back to [m][j] ----
#pragma unroll
    for (int jt = 0; jt < 7; ++jt) {
        int j0 = jt * 16 + h4 * 4;
        float4 bv;
        if (j0 + 3 < HIDN) bv = *(const float4*)(b1 + j0);
        else bv = make_float4(0.f, 0.f, 0.f, 0.f);
#pragma unroll
        for (int mt = 0; mt < 2; ++mt) {
            int mm = mt * 16 + l15;
            f32x4 a = acc1[jt][mt];
            ushort4 hv = make_ushort4(f2bf(fmaxf(a[0] + bv.x, 0.f)),
                                      f2bf(fmaxf(a[1] + bv.y, 0.f)),
                                      f2bf(fmaxf(a[2] + bv.z, 0.f)),
                                      f2bf(fmaxf(a[3] + bv.w, 0.f)));
            *(ushort4*)&hid_s[mm * 136 + j0] = hv;
        }
    }
    // same-wave LDS dependency; compiler inserts lgkmcnt waits (no cross-wave sharing)

    // ---- GEMM2: D2[m][o] = sum_j hid[m][j] * W2[j][o], K=128 ----
    f32x4 acc2[2][2] = {};
#pragma unroll
    for (int ks = 0; ks < 4; ++ks) {
        bf16x8 afr0 = *(const bf16x8*)&hid_s[l15 * 136 + ks * 32 + h4 * 8];
        bf16x8 afr1 = *(const bf16x8*)&hid_s[(16 + l15) * 136 + ks * 32 + h4 * 8];
        bf16x8 bfr0 = ld_w2(w2_lds, l15, ks * 32 + h4 * 8);
        bf16x8 bfr1 = ld_w2(w2_lds, 16 + l15, ks * 32 + h4 * 8);
        acc2[0][0] = __builtin_amdgcn_mfma_f32_16x16x32_bf16(afr0, bfr0, acc2[0][0], 0, 0, 0);
        acc2[0][1] = __builtin_amdgcn_mfma_f32_16x16x32_bf16(afr0, bfr1, acc2[0][1], 0, 0, 0);
        acc2[1][0] = __builtin_amdgcn_mfma_f32_16x16x32_bf16(afr1, bfr0, acc2[1][0], 0, 0, 0);
        acc2[1][1] = __builtin_amdgcn_mfma_f32_16x16x32_bf16(afr1, bfr1, acc2[1][1], 0, 0, 0);
    }

    // ---- t = relu(D2 + b2), store transposed tT[o][m] ----
#pragma unroll
    for (int ot = 0; ot < 2; ++ot) {
        int o = ot * 16 + l15;
        if (o < OUTU) {
            float b2v = b2[o];
#pragma unroll
            for (int mt = 0; mt < 2; ++mt) {
                int m0 = mt * 16 + h4 * 4;
                f32x4 a = acc2[mt][ot];
                float4 tv = make_float4(fmaxf(a[0] + b2v, 0.f), fmaxf(a[1] + b2v, 0.f),
                                        fmaxf(a[2] + b2v, 0.f), fmaxf(a[3] + b2v, 0.f));
                *(float4*)&tT_s[o * 36 + m0] = tv;
            }
        }
    }

    // ---- attention + softmax over heads ----
    {
        int mm = lane & 31;
        float tv[20];
#pragma unroll
        for (int o = 0; o < OUTU; ++o) tv[o] = tT_s[o * 36 + mm];
        float att[5];
#pragma unroll
        for (int h = 0; h < HHEADS; ++h) {
            float s = ba[h];
#pragma unroll
            for (int o = 0; o < OUTU; ++o) s += tv[o] * Wa[o * HHEADS + h];
            att[h] = fmaxf(s, 0.f);
        }
        float mx = att[0];
#pragma unroll
        for (int h = 1; h < HHEADS; ++h) mx = fmaxf(mx, att[h]);
        float e[5], sum = 0.f;
#pragma unroll
        for (int h = 0; h < HHEADS; ++h) { e[h] = __expf(att[h] - mx); sum += e[h]; }
        float inv = 1.f / sum;
        if (lane < 32) {
#pragma unroll
            for (int h = 0; h < HHEADS; ++h) pf_s[mm * HHEADS + h] = e[h] * inv;
        }
    }

    // ---- aggregate: out[n, h*20+o] = sum_k pf[h*32+k] * t[k][o] ----
#pragma unroll
    for (int pass = 0; pass < 2; ++pass) {
        int idx = pass * 64 + lane;
        if (idx < HHEADS * OUTU && active) {
            int h = idx / OUTU, o = idx % OUTU;
            float s = 0.f;
#pragma unroll
            for (int kk = 0; kk < 8; ++kk) {
                float4 p4 = *(const float4*)&pf_s[h * 32 + kk * 4];
                float4 t4 = *(const float4*)&tT_s[o * 36 + kk * 4];
                s += p4.x * t4.x + p4.y * t4.y + p4.z * t4.z + p4.w * t4.w;
            }
            out[(size_t)node * OUTW + idx] = s;
        }
    }
}

extern "C" void kernel_launch(void* const* d_in, const int* in_sizes, int n_in,
                              void* d_out, int out_size, void* d_ws, size_t ws_size,
                              hipStream_t stream) {
    const float* emb      = (const float*)d_in[0];
    const int*   node_idx = (const int*)d_in[1];
    const int*   neigh_idx= (const int*)d_in[2];
    const float* W1       = (const float*)d_in[3];
    const float* b1       = (const float*)d_in[4];
    const float* W2       = (const float*)d_in[5];
    const float* b2       = (const float*)d_in[6];
    const float* Wa       = (const float*)d_in[7];
    const float* ba       = (const float*)d_in[8];
    float* out = (float*)d_out;

    unsigned short* W1t = (unsigned short*)d_ws;            // 112*256 bf16 = 57344 B (pre-swizzled)
    unsigned short* W2t = W1t + 112 * 256;                  // 32*128 bf16  =  8192 B (pre-swizzled)

    int n = in_sizes[1];                                    // 20000 nodes
    int smem_bytes = 57344 + 8192 + NWAVES * 12224;         // 163328 B

    static bool attr_set = false;   // idempotent driver attr; not a stream op (graph-safe)
    if (!attr_set) {
        hipFuncSetAttribute((const void*)sa_main,
                            hipFuncAttributeMaxDynamicSharedMemorySize, smem_bytes);
        attr_set = true;
    }

    sa_prep<<<(112 * 256 + 32 * 128 + 255) / 256, 256, 0, stream>>>(W1, W2, W1t, W2t);
    sa_main<<<(n + NWAVES - 1) / NWAVES, NWAVES * 64, smem_bytes, stream>>>(
        emb, node_idx, neigh_idx, b1, b2, Wa, ba, W1t, W2t, out, n);
}

// Round 4
// 125.178 us; speedup vs baseline: 1.8314x; 1.1160x over previous
//
#include <hip/hip_runtime.h>
#include <hip/hip_bf16.h>

// Problem constants (fixed-shape problem)
#define KNB    32
#define DEMB   128
#define HIDN   100
#define OUTU   20
#define HHEADS 5
#define OUTW   228   // H*OUT + D = 100 + 128

#define NWAVES 8     // waves per block, 1 node per wave per iteration
#define NITER  2     // node-groups per block (weights staged once)

typedef __attribute__((ext_vector_type(4))) float f32x4;
typedef __attribute__((ext_vector_type(8))) short bf16x8;

__device__ __forceinline__ unsigned short f2bf(float f) {
    union { float f; unsigned u; } v; v.f = f;
    unsigned r = (v.u + 0x7fffu + ((v.u >> 16) & 1u)) >> 16;
    return (unsigned short)r;
}
__device__ __forceinline__ unsigned pkbf(float lo, float hi) {
    unsigned r;
    asm("v_cvt_pk_bf16_f32 %0, %1, %2" : "=v"(r) : "v"(lo), "v"(hi));
    return r;
}
__device__ __forceinline__ bf16x8 cvt8(float4 a, float4 b) {
    union { unsigned u[4]; bf16x8 v; } t;
    t.u[0] = pkbf(a.x, a.y); t.u[1] = pkbf(a.z, a.w);
    t.u[2] = pkbf(b.x, b.y); t.u[3] = pkbf(b.z, b.w);
    return t.v;
}

// ---------------- prep: FRAGMENT-MAJOR weight layouts ----------------
// W1f[(jt*8+ks)*64 + lane] = 8 bf16 of W1[d][j], j = jt*16+(lane&15), d = ks*32+(lane>>4)*8+e
//   -> GEMM1 A-frag read is ds_read_b128 at lane*16 + imm: conflict-free, no addr math.
// W2f[(ks*2+ot)*64 + lane] = 8 bf16 of W2[j][o], o = ot*16+(lane&15), j = ks*32+(lane>>4)*8+e
__global__ void sa_prep(const float* __restrict__ W1, const float* __restrict__ W2,
                        unsigned short* __restrict__ W1f, unsigned short* __restrict__ W2f) {
    int idx = blockIdx.x * 256 + threadIdx.x;          // 32768 total
    if (idx < 28672) {
        int e = idx & 7, lane = (idx >> 3) & 63, ks = (idx >> 9) & 7, jt = idx >> 12;
        int j = jt * 16 + (lane & 15);
        int d = ks * 32 + (lane >> 4) * 8 + e;
        W1f[idx] = (j < HIDN) ? f2bf(W1[d * HIDN + j]) : (unsigned short)0;
    } else {
        int i2 = idx - 28672;                          // < 4096
        int e = i2 & 7, lane = (i2 >> 3) & 63, ot = (i2 >> 9) & 1, ks = i2 >> 10;
        int o = ot * 16 + (lane & 15);
        int jj = ks * 32 + (lane >> 4) * 8 + e;
        W2f[i2] = (o < OUTU && jj < HIDN) ? f2bf(W2[jj * OUTU + o]) : (unsigned short)0;
    }
}

// ---------------- main: 8 waves/block, 1 node/wave, 2 node-groups/block ----------------
// LDS: 57344 (W1f) + 8192 (W2f) + 8*12224 (per-wave hid/tT/pf) = 163328 B -> 1 block/CU.
__global__ __launch_bounds__(NWAVES * 64, 2)
void sa_main(const float* __restrict__ emb,
             const int* __restrict__ node_idx,
             const int* __restrict__ neigh_idx,
             const float* __restrict__ b1,
             const float* __restrict__ b2,
             const float* __restrict__ Wa,
             const float* __restrict__ ba,
             const unsigned short* __restrict__ W1f,
             const unsigned short* __restrict__ W2f,
             float* __restrict__ out, int nnodes) {
    extern __shared__ char smem[];
    unsigned short* w1_lds = (unsigned short*)smem;                  // 57344 B
    unsigned short* w2_lds = (unsigned short*)(smem + 57344);        // 8192 B

    const int tid  = threadIdx.x;
    const int lane = tid & 63;
    const int wid  = tid >> 6;
    const int l15 = lane & 15, h4 = lane >> 4;

    char* wbase = smem + 65536 + wid * 12224;
    unsigned short* hid_s = (unsigned short*)wbase;                  // 32*136*2 = 8704 B
    float* tT_s = (float*)(wbase + 8704);                            // 20*36*4  = 2880 B
    float* pf_s = (float*)(wbase + 8704 + 2880);                     // 160*4    = 640 B

    const bf16x8* w1f_v = (const bf16x8*)w1_lds;
    const bf16x8* w2f_v = (const bf16x8*)w2_lds;

#pragma unroll
    for (int it = 0; it < NITER; ++it) {
        int node = blockIdx.x * (NWAVES * NITER) + it * NWAVES + wid;
        const int active = (node < nnodes);
        if (node >= nnodes) node = nnodes - 1;

        // ---- staging loads first (it==0): in vmem queue ahead of gathers ----
        float4 st[7], st2;
        if (it == 0) {
#pragma unroll
            for (int i = 0; i < 7; ++i) st[i] = ((const float4*)W1f)[tid + i * 512];
            st2 = ((const float4*)W2f)[tid];
        }

        // ---- issue ALL gather loads (f32), keep in flight ----
        const int* nip = neigh_idx + (size_t)node * KNB;
        const int r0 = nip[l15];
        const int r1 = nip[16 + l15];
        const int nid = node_idx[node];
        const float* p0 = emb + (size_t)r0 * DEMB + h4 * 8;
        const float* p1 = emb + (size_t)r1 * DEMB + h4 * 8;
        const float* pn = emb + (size_t)nid * DEMB + h4 * 8;

        float4 g0a[4], g0c[4], g1a[4], g1c[4], gna[4], gnc[4];
#pragma unroll
        for (int ks = 0; ks < 4; ++ks) {
            g0a[ks] = *(const float4*)(p0 + ks * 32);
            g0c[ks] = *(const float4*)(p0 + ks * 32 + 4);
            g1a[ks] = *(const float4*)(p1 + ks * 32);
            g1c[ks] = *(const float4*)(p1 + ks * 32 + 4);
            gna[ks] = *(const float4*)(pn + ks * 32);
            gnc[ks] = *(const float4*)(pn + ks * 32 + 4);
        }
        float4 nodecp;
        if (lane < 32) nodecp = ((const float4*)(emb + (size_t)nid * DEMB))[lane];

        // ---- write staged weights to LDS (waits only staging loads) ----
        if (it == 0) {
#pragma unroll
            for (int i = 0; i < 7; ++i) ((float4*)w1_lds)[tid + i * 512] = st[i];
            ((float4*)w2_lds)[tid] = st2;
        }

        __builtin_amdgcn_sched_barrier(0);   // pin: all loads issued above stay above

        // ---- convert gathers to bf16 B-fragments ----
        bf16x8 bf0[4], bf1[4], bnn[4];
#pragma unroll
        for (int ks = 0; ks < 4; ++ks) {
            bf0[ks] = cvt8(g0a[ks], g0c[ks]);
            bf1[ks] = cvt8(g1a[ks], g1c[ks]);
            bnn[ks] = cvt8(gna[ks], gnc[ks]);
        }

        if (it == 0) {
            // zero hid tail cols [112,128) once; cols [100,112) zero via zero W1f rows
            int r = lane >> 1, c = 112 + (lane & 1) * 8;
            ushort4 z = make_ushort4(0, 0, 0, 0);
            *(ushort4*)&hid_s[r * 136 + c] = z;
            *(ushort4*)&hid_s[r * 136 + c + 4] = z;
            __syncthreads();                 // the only cross-wave barrier
        }

        if (active && lane < 32)
            ((float4*)(out + (size_t)node * OUTW + HHEADS * OUTU))[lane] = nodecp;

        // ---- GEMM1: A-frags linear from LDS (lane*16 + imm), B in regs ----
        f32x4 acc1[7][2] = {};
#pragma unroll
        for (int ks = 0; ks < 8; ++ks) {
            bf16x8 bfr0 = (ks < 4) ? bf0[ks & 3] : bnn[ks & 3];
            bf16x8 bfr1 = (ks < 4) ? bf1[ks & 3] : bnn[ks & 3];
#pragma unroll
            for (int jt = 0; jt < 7; ++jt) {
                bf16x8 afr = w1f_v[(jt * 8 + ks) * 64 + lane];
                acc1[jt][0] = __builtin_amdgcn_mfma_f32_16x16x32_bf16(afr, bfr0, acc1[jt][0], 0, 0, 0);
                acc1[jt][1] = __builtin_amdgcn_mfma_f32_16x16x32_bf16(afr, bfr1, acc1[jt][1], 0, 0, 0);
            }
        }

        // ---- hid = relu(D1 + b1), bf16, transposed to [m][j] ----
#pragma unroll
        for (int jt = 0; jt < 7; ++jt) {
            int j0 = jt * 16 + h4 * 4;
            float4 bv;
            if (j0 + 3 < HIDN) bv = *(const float4*)(b1 + j0);
            else bv = make_float4(0.f, 0.f, 0.f, 0.f);
#pragma unroll
            for (int mt = 0; mt < 2; ++mt) {
                int mm = mt * 16 + l15;
                f32x4 a = acc1[jt][mt];
                ushort4 hv = make_ushort4(f2bf(fmaxf(a[0] + bv.x, 0.f)),
                                          f2bf(fmaxf(a[1] + bv.y, 0.f)),
                                          f2bf(fmaxf(a[2] + bv.z, 0.f)),
                                          f2bf(fmaxf(a[3] + bv.w, 0.f)));
                *(ushort4*)&hid_s[mm * 136 + j0] = hv;
            }
        }

        // ---- GEMM2: A = hid (LDS), B = W2 frags (LDS linear) ----
        f32x4 acc2[2][2] = {};
#pragma unroll
        for (int ks = 0; ks < 4; ++ks) {
            bf16x8 afr0 = *(const bf16x8*)&hid_s[l15 * 136 + ks * 32 + h4 * 8];
            bf16x8 afr1 = *(const bf16x8*)&hid_s[(16 + l15) * 136 + ks * 32 + h4 * 8];
            bf16x8 bfr0 = w2f_v[(ks * 2 + 0) * 64 + lane];
            bf16x8 bfr1 = w2f_v[(ks * 2 + 1) * 64 + lane];
            acc2[0][0] = __builtin_amdgcn_mfma_f32_16x16x32_bf16(afr0, bfr0, acc2[0][0], 0, 0, 0);
            acc2[0][1] = __builtin_amdgcn_mfma_f32_16x16x32_bf16(afr0, bfr1, acc2[0][1], 0, 0, 0);
            acc2[1][0] = __builtin_amdgcn_mfma_f32_16x16x32_bf16(afr1, bfr0, acc2[1][0], 0, 0, 0);
            acc2[1][1] = __builtin_amdgcn_mfma_f32_16x16x32_bf16(afr1, bfr1, acc2[1][1], 0, 0, 0);
        }

        // ---- t = relu(D2 + b2), store transposed tT[o][m] ----
#pragma unroll
        for (int ot = 0; ot < 2; ++ot) {
            int o = ot * 16 + l15;
            if (o < OUTU) {
                float b2v = b2[o];
#pragma unroll
                for (int mt = 0; mt < 2; ++mt) {
                    int m0 = mt * 16 + h4 * 4;
                    f32x4 a = acc2[mt][ot];
                    float4 tv = make_float4(fmaxf(a[0] + b2v, 0.f), fmaxf(a[1] + b2v, 0.f),
                                            fmaxf(a[2] + b2v, 0.f), fmaxf(a[3] + b2v, 0.f));
                    *(float4*)&tT_s[o * 36 + m0] = tv;
                }
            }
        }

        // ---- attention + softmax over heads ----
        {
            int mm = lane & 31;
            float tv[20];
#pragma unroll
            for (int o = 0; o < OUTU; ++o) tv[o] = tT_s[o * 36 + mm];
            float att[5];
#pragma unroll
            for (int h = 0; h < HHEADS; ++h) {
                float s = ba[h];
#pragma unroll
                for (int o = 0; o < OUTU; ++o) s += tv[o] * Wa[o * HHEADS + h];
                att[h] = fmaxf(s, 0.f);
            }
            float mx = att[0];
#pragma unroll
            for (int h = 1; h < HHEADS; ++h) mx = fmaxf(mx, att[h]);
            float e[5], sum = 0.f;
#pragma unroll
            for (int h = 0; h < HHEADS; ++h) { e[h] = __expf(att[h] - mx); sum += e[h]; }
            float inv = 1.f / sum;
            if (lane < 32) {
#pragma unroll
                for (int h = 0; h < HHEADS; ++h) pf_s[mm * HHEADS + h] = e[h] * inv;
            }
        }

        // ---- aggregate: out[n, h*20+o] = sum_k pf[h*32+k] * t[k][o] ----
#pragma unroll
        for (int pass = 0; pass < 2; ++pass) {
            int idx = pass * 64 + lane;
            if (idx < HHEADS * OUTU && active) {
                int h = idx / OUTU, o = idx % OUTU;
                float s = 0.f;
#pragma unroll
                for (int kk = 0; kk < 8; ++kk) {
                    float4 p4 = *(const float4*)&pf_s[h * 32 + kk * 4];
                    float4 t4 = *(const float4*)&tT_s[o * 36 + kk * 4];
                    s += p4.x * t4.x + p4.y * t4.y + p4.z * t4.z + p4.w * t4.w;
                }
                out[(size_t)node * OUTW + idx] = s;
            }
        }
        // no barrier between iterations: weights read-only, per-wave buffers private
    }
}

extern "C" void kernel_launch(void* const* d_in, const int* in_sizes, int n_in,
                              void* d_out, int out_size, void* d_ws, size_t ws_size,
                              hipStream_t stream) {
    const float* emb      = (const float*)d_in[0];
    const int*   node_idx = (const int*)d_in[1];
    const int*   neigh_idx= (const int*)d_in[2];
    const float* W1       = (const float*)d_in[3];
    const float* b1       = (const float*)d_in[4];
    const float* W2       = (const float*)d_in[5];
    const float* b2       = (const float*)d_in[6];
    const float* Wa       = (const float*)d_in[7];
    const float* ba       = (const float*)d_in[8];
    float* out = (float*)d_out;

    unsigned short* W1f = (unsigned short*)d_ws;            // 28672 bf16 = 57344 B (frag-major)
    unsigned short* W2f = W1f + 28672;                      // 4096 bf16  =  8192 B (frag-major)

    int n = in_sizes[1];                                    // 20000 nodes
    int smem_bytes = 57344 + 8192 + NWAVES * 12224;         // 163328 B

    static bool attr_set = false;   // idempotent driver attr; not a stream op (graph-safe)
    if (!attr_set) {
        hipFuncSetAttribute((const void*)sa_main,
                            hipFuncAttributeMaxDynamicSharedMemorySize, smem_bytes);
        attr_set = true;
    }

    sa_prep<<<128, 256, 0, stream>>>(W1, W2, W1f, W2f);
    int npb = NWAVES * NITER;                               // 16 nodes per block
    sa_main<<<(n + npb - 1) / npb, NWAVES * 64, smem_bytes, stream>>>(
        emb, node_idx, neigh_idx, b1, b2, Wa, ba, W1f, W2f, out, n);
}

// Round 5
// 101.803 us; speedup vs baseline: 2.2519x; 1.2296x over previous
//
#include <hip/hip_runtime.h>
#include <hip/hip_bf16.h>

// Problem constants (fixed-shape problem)
#define KNB    32
#define DEMB   128
#define HIDN   100
#define OUTU   20
#define HHEADS 5
#define OUTW   228   // H*OUT + D = 100 + 128

#define NWAVES 16    // waves per block, 1 node per wave

typedef __attribute__((ext_vector_type(4))) float f32x4;
typedef __attribute__((ext_vector_type(8))) short bf16x8;

__device__ __forceinline__ unsigned short f2bf(float f) {
    union { float f; unsigned u; } v; v.f = f;
    unsigned r = (v.u + 0x7fffu + ((v.u >> 16) & 1u)) >> 16;
    return (unsigned short)r;
}
__device__ __forceinline__ unsigned pkbf(float lo, float hi) {
    unsigned r;
    asm("v_cvt_pk_bf16_f32 %0, %1, %2" : "=v"(r) : "v"(lo), "v"(hi));
    return r;
}
__device__ __forceinline__ bf16x8 cvt8(float4 a, float4 b) {
    union { unsigned u[4]; bf16x8 v; } t;
    t.u[0] = pkbf(a.x, a.y); t.u[1] = pkbf(a.z, a.w);
    t.u[2] = pkbf(b.x, b.y); t.u[3] = pkbf(b.z, b.w);
    return t.v;
}

// ---------------- prep: FRAGMENT-MAJOR weight layouts ----------------
// W1f[(jt*8+ks)*64 + lane] = 8 bf16 of W1[d][j], j = jt*16+(lane&15), d = ks*32+(lane>>4)*8+e
// W2f[(ks*2+ot)*64 + lane] = 8 bf16 of W2[j][o], o = ot*16+(lane&15), j = ks*32+(lane>>4)*8+e
__global__ void sa_prep(const float* __restrict__ W1, const float* __restrict__ W2,
                        unsigned short* __restrict__ W1f, unsigned short* __restrict__ W2f) {
    int idx = blockIdx.x * 256 + threadIdx.x;          // 32768 total
    if (idx < 28672) {
        int e = idx & 7, lane = (idx >> 3) & 63, ks = (idx >> 9) & 7, jt = idx >> 12;
        int j = jt * 16 + (lane & 15);
        int d = ks * 32 + (lane >> 4) * 8 + e;
        W1f[idx] = (j < HIDN) ? f2bf(W1[d * HIDN + j]) : (unsigned short)0;
    } else {
        int i2 = idx - 28672;                          // < 4096
        int e = i2 & 7, lane = (i2 >> 3) & 63, ot = (i2 >> 9) & 1, ks = i2 >> 10;
        int o = ot * 16 + (lane & 15);
        int jj = ks * 32 + (lane >> 4) * 8 + e;
        W2f[i2] = (o < OUTU && jj < HIDN) ? f2bf(W2[jj * OUTU + o]) : (unsigned short)0;
    }
}

// ---------------- main: 16 waves/block, 1 node/wave; fused GEMM1->GEMM2 K-slices ----------------
// LDS: 57344 (W1f) + 8192 (W2f) + 16*6080 (per-wave stg/tT/pf) = 162816 B -> 1 block/CU, 16 waves.
__global__ __launch_bounds__(NWAVES * 64, 4)
void sa_main(const float* __restrict__ emb,
             const int* __restrict__ node_idx,
             const int* __restrict__ neigh_idx,
             const float* __restrict__ b1,
             const float* __restrict__ b2,
             const float* __restrict__ Wa,
             const float* __restrict__ ba,
             const unsigned short* __restrict__ W1f,
             const unsigned short* __restrict__ W2f,
             float* __restrict__ out, int nnodes) {
    extern __shared__ char smem[];
    unsigned short* w1_lds = (unsigned short*)smem;                  // 57344 B
    unsigned short* w2_lds = (unsigned short*)(smem + 57344);        // 8192 B

    const int tid  = threadIdx.x;
    const int lane = tid & 63;
    const int wid  = tid >> 6;
    const int l15 = lane & 15, h4 = lane >> 4;

    char* wbase = smem + 65536 + wid * 6080;
    char* stgB  = wbase;                              // 32 rows x 80 B = 2560 B (bf16 32x32 slice, stride 40 shorts)
    float* tT_s = (float*)(wbase + 2560);             // 20*36*4 = 2880 B
    float* pf_s = (float*)(wbase + 2560 + 2880);      // 160*4   = 640 B

    const bf16x8* w1f_v = (const bf16x8*)w1_lds;
    const bf16x8* w2f_v = (const bf16x8*)w2_lds;

    int node = blockIdx.x * NWAVES + wid;
    const int active = (node < nnodes);
    if (node >= nnodes) node = nnodes - 1;

    // ---- staging loads first: oldest in vmem queue ----
    float4 st[4];
#pragma unroll
    for (int i = 0; i < 4; ++i) st[i] = ((const float4*)W1f)[tid + i * 1024];  // covers W1f+W2f (contiguous)

    // ---- issue ALL gather loads (f32), keep in flight ----
    const int* nip = neigh_idx + (size_t)node * KNB;
    const int r0 = nip[l15];
    const int r1 = nip[16 + l15];
    const int nid = node_idx[node];
    const float* p0 = emb + (size_t)r0 * DEMB + h4 * 8;
    const float* p1 = emb + (size_t)r1 * DEMB + h4 * 8;
    const float* pn = emb + (size_t)nid * DEMB + h4 * 8;

    float4 g0a[4], g0c[4], g1a[4], g1c[4], gna[4], gnc[4];
#pragma unroll
    for (int ks = 0; ks < 4; ++ks) {
        g0a[ks] = *(const float4*)(p0 + ks * 32);
        g0c[ks] = *(const float4*)(p0 + ks * 32 + 4);
        g1a[ks] = *(const float4*)(p1 + ks * 32);
        g1c[ks] = *(const float4*)(p1 + ks * 32 + 4);
        gna[ks] = *(const float4*)(pn + ks * 32);
        gnc[ks] = *(const float4*)(pn + ks * 32 + 4);
    }
    float4 nodecp;
    if (lane < 32) nodecp = ((const float4*)(emb + (size_t)nid * DEMB))[lane];

    // ---- write staged weights to LDS (waits only the 4 oldest loads) ----
#pragma unroll
    for (int i = 0; i < 4; ++i) ((float4*)w1_lds)[tid + i * 1024] = st[i];

    __syncthreads();   // the only cross-wave barrier

    __builtin_amdgcn_sched_barrier(0);   // keep all loads issued above

    if (active && lane < 32)
        ((float4*)(out + (size_t)node * OUTW + HHEADS * OUTU))[lane] = nodecp;

    // ---- convert gathers to bf16 B-fragments (as they land) ----
    bf16x8 bf0[4], bf1[4], bnn[4];
#pragma unroll
    for (int ks = 0; ks < 4; ++ks) {
        bf0[ks] = cvt8(g0a[ks], g0c[ks]);
        bf1[ks] = cvt8(g1a[ks], g1c[ks]);
        bnn[ks] = cvt8(gna[ks], gnc[ks]);
    }

    // ---- fused GEMM1 -> GEMM2 over K-slices of 32 hidden units ----
    // GEMM1: D1[j][m] = sum_d W1[d][j]*x[m][d]; lane holds col m=l15, rows j=jt*16+h4*4+q.
    // stage slice [m][j_local] bf16 (stride 40 shorts = 80 B), then GEMM2 K-step ks.
    f32x4 acc2[2][2] = {};
#pragma unroll
    for (int ks = 0; ks < 4; ++ks) {
#pragma unroll
        for (int jt2 = 0; jt2 < 2; ++jt2) {
            const int jt = ks * 2 + jt2;
            const int co = jt2 * 32 + h4 * 8;              // byte col offset in stage row
            if (jt < 7) {
                f32x4 a0 = {0.f, 0.f, 0.f, 0.f}, a1 = {0.f, 0.f, 0.f, 0.f};
#pragma unroll
                for (int kk = 0; kk < 8; ++kk) {
                    bf16x8 afr = w1f_v[(jt * 8 + kk) * 64 + lane];
                    bf16x8 bb0 = (kk < 4) ? bf0[kk & 3] : bnn[kk & 3];
                    bf16x8 bb1 = (kk < 4) ? bf1[kk & 3] : bnn[kk & 3];
                    a0 = __builtin_amdgcn_mfma_f32_16x16x32_bf16(afr, bb0, a0, 0, 0, 0);
                    a1 = __builtin_amdgcn_mfma_f32_16x16x32_bf16(afr, bb1, a1, 0, 0, 0);
                }
                const int j0 = jt * 16 + h4 * 4;
                float4 bv;
                if (j0 + 3 < HIDN) bv = *(const float4*)(b1 + j0);
                else bv = make_float4(0.f, 0.f, 0.f, 0.f);   // j>=100: acc is 0 there too
                unsigned u00 = pkbf(fmaxf(a0[0] + bv.x, 0.f), fmaxf(a0[1] + bv.y, 0.f));
                unsigned u01 = pkbf(fmaxf(a0[2] + bv.z, 0.f), fmaxf(a0[3] + bv.w, 0.f));
                unsigned u10 = pkbf(fmaxf(a1[0] + bv.x, 0.f), fmaxf(a1[1] + bv.y, 0.f));
                unsigned u11 = pkbf(fmaxf(a1[2] + bv.z, 0.f), fmaxf(a1[3] + bv.w, 0.f));
                *(uint2*)(stgB + l15 * 80 + co)        = make_uint2(u00, u01);
                *(uint2*)(stgB + (16 + l15) * 80 + co) = make_uint2(u10, u11);
            } else {   // jt==7: j in [112,128) -> zeros
                *(uint2*)(stgB + l15 * 80 + co)        = make_uint2(0u, 0u);
                *(uint2*)(stgB + (16 + l15) * 80 + co) = make_uint2(0u, 0u);
            }
        }
        // GEMM2 K-step ks: A = staged hid slice (rows m, k = j_local), B = W2 frags
        bf16x8 afr0 = *(const bf16x8*)(stgB + l15 * 80 + h4 * 16);
        bf16x8 afr1 = *(const bf16x8*)(stgB + (16 + l15) * 80 + h4 * 16);
        bf16x8 bfr0 = w2f_v[(ks * 2 + 0) * 64 + lane];
        bf16x8 bfr1 = w2f_v[(ks * 2 + 1) * 64 + lane];
        acc2[0][0] = __builtin_amdgcn_mfma_f32_16x16x32_bf16(afr0, bfr0, acc2[0][0], 0, 0, 0);
        acc2[0][1] = __builtin_amdgcn_mfma_f32_16x16x32_bf16(afr0, bfr1, acc2[0][1], 0, 0, 0);
        acc2[1][0] = __builtin_amdgcn_mfma_f32_16x16x32_bf16(afr1, bfr0, acc2[1][0], 0, 0, 0);
        acc2[1][1] = __builtin_amdgcn_mfma_f32_16x16x32_bf16(afr1, bfr1, acc2[1][1], 0, 0, 0);
    }

    // ---- t = relu(D2 + b2), store transposed tT[o][m] ----
#pragma unroll
    for (int ot = 0; ot < 2; ++ot) {
        int o = ot * 16 + l15;
        if (o < OUTU) {
            float b2v = b2[o];
#pragma unroll
            for (int mt = 0; mt < 2; ++mt) {
                int m0 = mt * 16 + h4 * 4;
                f32x4 a = acc2[mt][ot];
                float4 tv = make_float4(fmaxf(a[0] + b2v, 0.f), fmaxf(a[1] + b2v, 0.f),
                                        fmaxf(a[2] + b2v, 0.f), fmaxf(a[3] + b2v, 0.f));
                *(float4*)&tT_s[o * 36 + m0] = tv;
            }
        }
    }

    // ---- attention + softmax over heads ----
    {
        int mm = lane & 31;
        float tv[20];
#pragma unroll
        for (int o = 0; o < OUTU; ++o) tv[o] = tT_s[o * 36 + mm];
        float att[5];
#pragma unroll
        for (int h = 0; h < HHEADS; ++h) {
            float s = ba[h];
#pragma unroll
            for (int o = 0; o < OUTU; ++o) s += tv[o] * Wa[o * HHEADS + h];
            att[h] = fmaxf(s, 0.f);
        }
        float mx = att[0];
#pragma unroll
        for (int h = 1; h < HHEADS; ++h) mx = fmaxf(mx, att[h]);
        float e[5], sum = 0.f;
#pragma unroll
        for (int h = 0; h < HHEADS; ++h) { e[h] = __expf(att[h] - mx); sum += e[h]; }
        float inv = 1.f / sum;
        if (lane < 32) {
#pragma unroll
            for (int h = 0; h < HHEADS; ++h) pf_s[mm * HHEADS + h] = e[h] * inv;
        }
    }

    // ---- aggregate: out[n, h*20+o] = sum_k pf[h*32+k] * t[k][o]  (reshape-faithful) ----
#pragma unroll
    for (int pass = 0; pass < 2; ++pass) {
        int idx = pass * 64 + lane;
        if (idx < HHEADS * OUTU && active) {
            int h = idx / OUTU, o = idx % OUTU;
            float s = 0.f;
#pragma unroll
            for (int kk = 0; kk < 8; ++kk) {
                float4 p4 = *(const float4*)&pf_s[h * 32 + kk * 4];
                float4 t4 = *(const float4*)&tT_s[o * 36 + kk * 4];
                s += p4.x * t4.x + p4.y * t4.y + p4.z * t4.z + p4.w * t4.w;
            }
            out[(size_t)node * OUTW + idx] = s;
        }
    }
}

extern "C" void kernel_launch(void* const* d_in, const int* in_sizes, int n_in,
                              void* d_out, int out_size, void* d_ws, size_t ws_size,
                              hipStream_t stream) {
    const float* emb      = (const float*)d_in[0];
    const int*   node_idx = (const int*)d_in[1];
    const int*   neigh_idx= (const int*)d_in[2];
    const float* W1       = (const float*)d_in[3];
    const float* b1       = (const float*)d_in[4];
    const float* W2       = (const float*)d_in[5];
    const float* b2       = (const float*)d_in[6];
    const float* Wa       = (const float*)d_in[7];
    const float* ba       = (const float*)d_in[8];
    float* out = (float*)d_out;

    unsigned short* W1f = (unsigned short*)d_ws;            // 28672 bf16 = 57344 B (frag-major)
    unsigned short* W2f = W1f + 28672;                      // 4096 bf16  =  8192 B (frag-major, contiguous)

    int n = in_sizes[1];                                    // 20000 nodes
    int smem_bytes = 57344 + 8192 + NWAVES * 6080;          // 162816 B

    static bool attr_set = false;   // idempotent driver attr; not a stream op (graph-safe)
    if (!attr_set) {
        hipFuncSetAttribute((const void*)sa_main,
                            hipFuncAttributeMaxDynamicSharedMemorySize, smem_bytes);
        attr_set = true;
    }

    sa_prep<<<128, 256, 0, stream>>>(W1, W2, W1f, W2f);
    sa_main<<<(n + NWAVES - 1) / NWAVES, NWAVES * 64, smem_bytes, stream>>>(
        emb, node_idx, neigh_idx, b1, b2, Wa, ba, W1f, W2f, out, n);
}